// Round 2
// baseline (5351.904 us; speedup 1.0000x reference)
//
#include <hip/hip_runtime.h>

typedef unsigned short u16;
typedef __attribute__((ext_vector_type(8))) short bf16x8;
typedef __attribute__((ext_vector_type(4))) float f32x4;

__device__ __forceinline__ float bf2f(u16 u) {
  union { unsigned u; float f; } v; v.u = ((unsigned)u) << 16; return v.f;
}
__device__ __forceinline__ u16 f2bf(float f) {
  union { float f; unsigned u; } v; v.f = f;
  unsigned r = v.u + 0x7FFFu + ((v.u >> 16) & 1u);
  return (u16)(r >> 16);
}

// ---------------- scratch layout (bytes inside d_out scores region) ----------
// scores region (first 262,144,000 B of d_out) is only written by the final
// log_softmax kernel -> free scratch for everything before it.
constexpr size_t OFF_WCAT  = 0;             // bf16 [32000][1536]
constexpr size_t OFF_WSEM  = 98304000;      // bf16 [32000][1024]
constexpr size_t OFF_GI0   = 163840000;     // f32  [2048][3072]
constexpr size_t OFF_XOUT  = 189005824;     // bf16 [2048][1536]  (h1 | emb)
constexpr size_t OFF_H0ALL = 195297280;     // bf16 [128][16][1024]
constexpr size_t OFF_WIH0E = 199491584;     // bf16 [3072][512]
constexpr size_t OFF_WIH0S = 202637312;     // bf16 [3072][1024]  (syn slice)
constexpr size_t OFF_WHH0  = 208928768;     // bf16 [3072][1024]
constexpr size_t OFF_WIH1  = 215220224;     // bf16 [3072][1024]
constexpr size_t OFF_WHH1  = 221511680;     // bf16 [3072][1024]
constexpr size_t OFF_SYNB  = 227803136;     // bf16 [128][1024] (rows>=16 zero)
constexpr size_t OFF_SEMB  = 228065280;     // bf16 [128][1024]
constexpr size_t OFF_BASE0 = 228327424;     // f32  [128][3072]
constexpr size_t OFF_BASEO = 229900288;     // f32  [128][32000]
constexpr size_t OFF_H0IBF = 246284288;     // bf16 [16][1024]
constexpr size_t OFF_H1IBF = 246317056;     // bf16 [16][1024]
constexpr size_t OFF_FLAGS = 246349824;     // int [256] barrier flags
// real outputs
constexpr size_t OFF_HIDF  = 262144000;     // f32 [2][16][1024]
constexpr size_t OFF_LAST  = 262275072;     // f32 [16][1024]
constexpr size_t OFF_LOGIT = 262340608;     // f32 [2048][32000]

// ---------------- fp32 -> bf16 2D convert ------------------------------------
__global__ __launch_bounds__(256) void conv_bf16_k(
    const float* __restrict__ src, u16* __restrict__ dst,
    int rows, int cols8, int sld, int soff, int dld, int doff) {
  int t = blockIdx.x * 256 + threadIdx.x;
  if (t >= rows * cols8) return;
  int r = t / cols8, c = (t - r * cols8) * 8;
  const float* s = src + (size_t)r * sld + soff + c;
  float4 a = *(const float4*)s;
  float4 b = *(const float4*)(s + 4);
  bf16x8 o;
  o[0] = (short)f2bf(a.x); o[1] = (short)f2bf(a.y);
  o[2] = (short)f2bf(a.z); o[3] = (short)f2bf(a.w);
  o[4] = (short)f2bf(b.x); o[5] = (short)f2bf(b.y);
  o[6] = (short)f2bf(b.z); o[7] = (short)f2bf(b.w);
  *(bf16x8*)(dst + (size_t)r * dld + doff + c) = o;
}

// ---------------- pack [16][1024] f32 -> [128][1024] bf16, rows>=16 zeroed ---
__global__ __launch_bounds__(256) void pack_pad_bf16_k(
    const float* __restrict__ src, u16* __restrict__ dst) {
  int t = blockIdx.x * 256 + threadIdx.x;   // 128*128 jobs
  int row = t >> 7, c = (t & 127) * 8;
  bf16x8 o = {0, 0, 0, 0, 0, 0, 0, 0};
  if (row < 16) {
    const float* s = src + row * 1024 + c;
    float4 a = *(const float4*)s;
    float4 b = *(const float4*)(s + 4);
    o[0] = (short)f2bf(a.x); o[1] = (short)f2bf(a.y);
    o[2] = (short)f2bf(a.z); o[3] = (short)f2bf(a.w);
    o[4] = (short)f2bf(b.x); o[5] = (short)f2bf(b.y);
    o[6] = (short)f2bf(b.z); o[7] = (short)f2bf(b.w);
  }
  *(bf16x8*)(dst + (size_t)row * 1024 + c) = o;
}

// ---------------- embedding gather -> bf16 into XOUT[:,1024:1536] ------------
__global__ __launch_bounds__(256) void gather_emb_k(
    const int* __restrict__ seq, const float* __restrict__ table,
    u16* __restrict__ xout) {
  int t0 = blockIdx.x * 256 + threadIdx.x;  // 2048 rows * 64 chunks
  int tb = t0 >> 6, c = (t0 & 63) * 8;
  int tt = tb >> 4, b = tb & 15;
  int tok = seq[b * 128 + tt];              // input_seq is [B=16][T=128]
  const float* s = table + (size_t)tok * 512 + c;
  float4 a = *(const float4*)s;
  float4 bb = *(const float4*)(s + 4);
  bf16x8 o;
  o[0] = (short)f2bf(a.x);  o[1] = (short)f2bf(a.y);
  o[2] = (short)f2bf(a.z);  o[3] = (short)f2bf(a.w);
  o[4] = (short)f2bf(bb.x); o[5] = (short)f2bf(bb.y);
  o[6] = (short)f2bf(bb.z); o[7] = (short)f2bf(bb.w);
  *(bf16x8*)(xout + (size_t)tb * 1536 + 1024 + c) = o;
}

// ---------------- init bf16 h + barrier flags --------------------------------
__global__ __launch_bounds__(256) void init_h_k(
    const float* __restrict__ hidden, u16* __restrict__ h0b,
    u16* __restrict__ h1b, int* __restrict__ flags) {
  int i = blockIdx.x * 256 + threadIdx.x;   // 16384
  h0b[i] = f2bf(hidden[i]);
  h1b[i] = f2bf(hidden[16384 + i]);
  if (i < 256) flags[i] = 0;
}

// ---------------- persistent 2-layer pipelined GRU recurrence ----------------
// 256 blocks x 256 thr. Blocks 0..127: layer 0 (8 j each). Blocks 128..255:
// layer 1 (8 j each), computing gi1 = h0_t @ Wih1.T inline.
// Stage s: L0 computes t=s (s<128); L1 computes t=s-1 (s>=1). 129 stages.
// Weights LDS-resident in MFMA-fragment order:
//   idx_u16 = (chain*32+ks)*512 + q*128 + col*8 + e ; (col=lane&15, q=lane>>4)
//   chain even: cols 0..7 gate r (j=jb+col), 8..15 gate z; chain odd: n | pad.
__global__ __launch_bounds__(256, 1) void gru_persist_k(
    const float* __restrict__ hidden, const u16* __restrict__ h0i,
    const u16* __restrict__ h1i, const float* __restrict__ gi0,
    const u16* __restrict__ Whh0, const u16* __restrict__ Wih1,
    const u16* __restrict__ Whh1, const float* __restrict__ bhh0,
    const float* __restrict__ bih1, const float* __restrict__ bhh1,
    u16* __restrict__ h0all, u16* __restrict__ xout,
    float* __restrict__ hidf, float* __restrict__ last,
    int* __restrict__ flags) {
  extern __shared__ u16 lds[];              // 131072 B weights + 4096 B C-tiles
  const int tid = threadIdx.x, bid = blockIdx.x;
  const int wave = tid >> 6, lane = tid & 63;
  const bool isL1 = bid >= 128;
  const int jb = (bid & 127) * 8;
  float* Clds = (float*)(lds + 65536);      // 4 tiles x 256 f32

  // zero weight region (covers pad cols)
  for (int i = tid; i < 65536; i += 256) lds[i] = 0;
  __syncthreads();

  // stage weights into LDS
  const int nch = isL1 ? 4 : 2;
  for (int job = tid; job < nch * 512; job += 256) {
    int chain = job >> 9, rem = job & 511, col = rem >> 5, ks = rem & 31;
    int ct = chain & 1;
    if (ct == 1 && col >= 8) continue;      // pad cols stay zero
    int gate = ct ? 2 : (col >> 3);
    const u16* W = isL1 ? (chain < 2 ? Wih1 : Whh1) : Whh0;
    const u16* src = W + (size_t)(gate * 1024 + jb + (col & 7)) * 1024 + ks * 32;
    u16* dst = lds + (chain * 32 + ks) * 512 + col * 8;
#pragma unroll
    for (int q = 0; q < 4; ++q)
      *(uint4*)(dst + q * 128) = *(const uint4*)(src + q * 8);
  }

  // epilogue thread identity + fp32 recurrent state in registers
  const int eb = tid & 15, ej = tid >> 4;   // valid for tid<128
  float hprev = 0.f, bR = 0.f, bZ = 0.f, bN = 0.f, iR = 0.f, iZ = 0.f, iN = 0.f;
  if (tid < 128) {
    hprev = hidden[(isL1 ? 16384 : 0) + eb * 1024 + jb + ej];
    const float* bh = isL1 ? bhh1 : bhh0;
    bR = bh[jb + ej]; bZ = bh[1024 + jb + ej]; bN = bh[2048 + jb + ej];
    if (isL1) {
      iR = bih1[jb + ej]; iZ = bih1[1024 + jb + ej]; iN = bih1[2048 + jb + ej];
    }
  }
  __syncthreads();

  const int arow = lane & 15, aq = lane >> 4;
  for (int s = 0; s < 129; ++s) {
    const bool active = isL1 ? (s >= 1) : (s < 128);
    if (active) {
      // pick this wave's MFMA chain and A-operand source
      int chain, ks0, ksn, astr;
      const u16* asrc;
      if (!isL1) {
        chain = wave & 1; ks0 = (wave >> 1) * 16; ksn = 16;
        asrc = (s == 0) ? h0i : h0all + (size_t)(s - 1) * 16 * 1024; astr = 1024;
      } else {
        chain = wave; ks0 = 0; ksn = 32;
        if (wave < 2) { asrc = h0all + (size_t)(s - 1) * 16 * 1024; astr = 1024; }
        else if (s == 1) { asrc = h1i; astr = 1024; }
        else { asrc = xout + (size_t)(s - 2) * 16 * 1536; astr = 1536; }
      }
      const u16* abase = asrc + (size_t)arow * astr + aq * 8;
      const u16* bbase = lds + (size_t)chain * 32 * 512 + aq * 128 + arow * 8;
      f32x4 acc = {0.f, 0.f, 0.f, 0.f};
#pragma unroll 8
      for (int ks = ks0; ks < ks0 + ksn; ++ks) {
        bf16x8 af = *(const bf16x8*)(abase + ks * 32);
        bf16x8 bf = *(const bf16x8*)(bbase + ks * 512);
        acc = __builtin_amdgcn_mfma_f32_16x16x32_bf16(af, bf, acc, 0, 0, 0);
      }
      float* ct = Clds + wave * 256;        // [row][col], row=b
      int r0 = aq * 4;
      ct[(r0 + 0) * 16 + arow] = acc[0];
      ct[(r0 + 1) * 16 + arow] = acc[1];
      ct[(r0 + 2) * 16 + arow] = acc[2];
      ct[(r0 + 3) * 16 + arow] = acc[3];
    }
    __syncthreads();
    if (active && tid < 128) {
      int t = isL1 ? s - 1 : s;
      float gr, gz, gn, ir, iz, inn;
      int e0 = eb * 16 + ej, e1 = eb * 16 + 8 + ej;
      if (!isL1) {
        gr = Clds[e0] + Clds[512 + e0];
        gz = Clds[e1] + Clds[512 + e1];
        gn = Clds[256 + e0] + Clds[768 + e0];
        const float* g = gi0 + ((size_t)t * 16 + eb) * 3072;
        ir = g[jb + ej]; iz = g[1024 + jb + ej]; inn = g[2048 + jb + ej];
      } else {
        ir = Clds[e0] + iR; iz = Clds[e1] + iZ; inn = Clds[256 + e0] + iN;
        gr = Clds[512 + e0]; gz = Clds[512 + e1]; gn = Clds[768 + e0];
      }
      float r = 1.f / (1.f + __expf(-(ir + gr + bR)));
      float z = 1.f / (1.f + __expf(-(iz + gz + bZ)));
      float n = tanhf(inn + r * (gn + bN));
      float hnew = (1.f - z) * n + z * hprev;
      hprev = hnew;
      u16 hb = f2bf(hnew);
      if (!isL1) {
        h0all[((size_t)t * 16 + eb) * 1024 + jb + ej] = hb;
        if (t == 127) hidf[eb * 1024 + jb + ej] = hnew;
      } else {
        xout[((size_t)t * 16 + eb) * 1536 + jb + ej] = hb;
        if (t == 127) {
          hidf[16384 + eb * 1024 + jb + ej] = hnew;
          last[eb * 1024 + jb + ej] = hnew;
        }
      }
    }
    // device-scope barrier (all 256 blocks co-resident: 1 block/CU by LDS)
    if (s < 128) {
      __syncthreads();
      if (tid == 0) {
        __threadfence();
        __hip_atomic_store(flags + bid, s + 1, __ATOMIC_RELEASE,
                           __HIP_MEMORY_SCOPE_AGENT);
      }
      if (tid < 64) {
        const int target = s + 1;
        for (;;) {
          int m0 = __hip_atomic_load(flags + lane * 4 + 0, __ATOMIC_ACQUIRE,
                                     __HIP_MEMORY_SCOPE_AGENT);
          int m1 = __hip_atomic_load(flags + lane * 4 + 1, __ATOMIC_ACQUIRE,
                                     __HIP_MEMORY_SCOPE_AGENT);
          int m2 = __hip_atomic_load(flags + lane * 4 + 2, __ATOMIC_ACQUIRE,
                                     __HIP_MEMORY_SCOPE_AGENT);
          int m3 = __hip_atomic_load(flags + lane * 4 + 3, __ATOMIC_ACQUIRE,
                                     __HIP_MEMORY_SCOPE_AGENT);
          int mn = min(min(m0, m1), min(m2, m3));
          if (__all(mn >= target)) break;
        }
      }
      __syncthreads();
    }
  }
}

// ---------------- bf16 MFMA GEMM: C[M,N] = A[M,K] @ B[N,K].T (+ add) ---------
// MODE 1: add[(row&15)*N + col]; 2: add[col]
template <int MODE>
__global__ __launch_bounds__(256) void gemm_bt_k(
    const u16* __restrict__ A, int lda, const u16* __restrict__ Bw, int ldb,
    float* __restrict__ C, int ldc, const float* __restrict__ add,
    int N, int K) {
  __shared__ u16 Asm_[128 * 32];
  __shared__ u16 Bsm_[128 * 32];
  const int m0 = blockIdx.x * 128, n0 = blockIdx.y * 128;
  const int tid = threadIdx.x, wave = tid >> 6, lane = tid & 63;
  const int wm = (wave >> 1) * 64, wn = (wave & 1) * 64;
  const int lrow = lane & 15, lk = (lane >> 4) * 8;
  f32x4 acc[4][4] = {};
  for (int k0 = 0; k0 < K; k0 += 32) {
    __syncthreads();
#pragma unroll
    for (int q = 0; q < 2; ++q) {
      int c = (wave * 2 + q) * 64 + lane;
      int row = c >> 2, seg = c & 3;
      const u16* src = A + (size_t)(m0 + row) * lda + k0 + seg * 8;
      u16* dst = Asm_ + (wave * 2 + q) * 512;
      __builtin_amdgcn_global_load_lds(
          (const __attribute__((address_space(1))) void*)src,
          (__attribute__((address_space(3))) void*)dst, 16, 0, 0);
    }
#pragma unroll
    for (int q = 0; q < 2; ++q) {
      int c = (wave * 2 + q) * 64 + lane;
      int row = c >> 2, seg = c & 3;
      const u16* src = Bw + (size_t)(n0 + row) * ldb + k0 + seg * 8;
      u16* dst = Bsm_ + (wave * 2 + q) * 512;
      __builtin_amdgcn_global_load_lds(
          (const __attribute__((address_space(1))) void*)src,
          (__attribute__((address_space(3))) void*)dst, 16, 0, 0);
    }
    asm volatile("s_waitcnt vmcnt(0)" ::: "memory");
    __syncthreads();
    bf16x8 af[4], bfr[4];
#pragma unroll
    for (int i = 0; i < 4; ++i) {
      af[i]  = *(const bf16x8*)(Asm_ + (wm + i * 16 + lrow) * 32 + lk);
      bfr[i] = *(const bf16x8*)(Bsm_ + (wn + i * 16 + lrow) * 32 + lk);
    }
#pragma unroll
    for (int i = 0; i < 4; ++i)
#pragma unroll
      for (int j = 0; j < 4; ++j)
        acc[i][j] = __builtin_amdgcn_mfma_f32_16x16x32_bf16(
            af[i], bfr[j], acc[i][j], 0, 0, 0);
  }
  const int lr4 = (lane >> 4) * 4;
#pragma unroll
  for (int i = 0; i < 4; ++i) {
#pragma unroll
    for (int j = 0; j < 4; ++j) {
      int gc = n0 + wn + j * 16 + lrow;
#pragma unroll
      for (int r = 0; r < 4; ++r) {
        int gr = m0 + wm + i * 16 + lr4 + r;
        float v = acc[i][j][r];
        if (MODE == 1) v += add[(gr & 15) * N + gc];
        else if (MODE == 2) v += add[gc];
        C[(size_t)gr * ldc + gc] = v;
      }
    }
  }
}

// ---------------- row-wise log_softmax (rows of 32000) -----------------------
__global__ __launch_bounds__(256) void log_softmax_k(
    const float* __restrict__ logits, float* __restrict__ scores) {
  int row = blockIdx.x;
  const float* x = logits + (size_t)row * 32000;
  float* y = scores + (size_t)row * 32000;
  __shared__ float red[8];
  int tid = threadIdx.x;
  float m = -3.4e38f;
  for (int idx = tid * 4; idx < 32000; idx += 1024) {
    float4 v = *(const float4*)(x + idx);
    m = fmaxf(m, fmaxf(fmaxf(v.x, v.y), fmaxf(v.z, v.w)));
  }
  for (int off = 32; off; off >>= 1) m = fmaxf(m, __shfl_xor(m, off));
  if ((tid & 63) == 0) red[tid >> 6] = m;
  __syncthreads();
  m = fmaxf(fmaxf(red[0], red[1]), fmaxf(red[2], red[3]));
  float s = 0.f;
  for (int idx = tid * 4; idx < 32000; idx += 1024) {
    float4 v = *(const float4*)(x + idx);
    s += __expf(v.x - m) + __expf(v.y - m) + __expf(v.z - m) + __expf(v.w - m);
  }
  for (int off = 32; off; off >>= 1) s += __shfl_xor(s, off);
  if ((tid & 63) == 0) red[4 + (tid >> 6)] = s;
  __syncthreads();
  s = red[4] + red[5] + red[6] + red[7];
  float lse = m + logf(s);
  for (int idx = tid * 4; idx < 32000; idx += 1024) {
    float4 v = *(const float4*)(x + idx);
    float4 o;
    o.x = v.x - lse; o.y = v.y - lse; o.z = v.z - lse; o.w = v.w - lse;
    *(float4*)(y + idx) = o;
  }
}

// =============================================================================
extern "C" void kernel_launch(void* const* d_in, const int* in_sizes, int n_in,
                              void* d_out, int out_size, void* d_ws,
                              size_t ws_size, hipStream_t stream) {
  const int*   seq    = (const int*)d_in[0];
  const float* sem    = (const float*)d_in[2];
  const float* syn    = (const float*)d_in[3];
  const float* hidden = (const float*)d_in[4];
  const float* table  = (const float*)d_in[5];
  const float* Wih0   = (const float*)d_in[6];
  const float* Whh0   = (const float*)d_in[7];
  const float* bih0   = (const float*)d_in[8];
  const float* bhh0   = (const float*)d_in[9];
  const float* Wih1   = (const float*)d_in[10];
  const float* Whh1   = (const float*)d_in[11];
  const float* bih1   = (const float*)d_in[12];
  const float* bhh1   = (const float*)d_in[13];
  const float* Wout   = (const float*)d_in[14];
  const float* bout   = (const float*)d_in[15];

  char* base = (char*)d_out;
  float* scores = (float*)base;
  u16*   WCAT   = (u16*)(base + OFF_WCAT);
  u16*   WSEM   = (u16*)(base + OFF_WSEM);
  float* GI0    = (float*)(base + OFF_GI0);
  u16*   XOUT   = (u16*)(base + OFF_XOUT);
  u16*   H0ALL  = (u16*)(base + OFF_H0ALL);
  u16*   WIH0E  = (u16*)(base + OFF_WIH0E);
  u16*   WIH0S  = (u16*)(base + OFF_WIH0S);
  u16*   WHH0B  = (u16*)(base + OFF_WHH0);
  u16*   WIH1B  = (u16*)(base + OFF_WIH1);
  u16*   WHH1B  = (u16*)(base + OFF_WHH1);
  u16*   SYNB   = (u16*)(base + OFF_SYNB);
  u16*   SEMB   = (u16*)(base + OFF_SEMB);
  float* BASE0  = (float*)(base + OFF_BASE0);
  float* BASEO  = (float*)(base + OFF_BASEO);
  u16*   H0IBF  = (u16*)(base + OFF_H0IBF);
  u16*   H1IBF  = (u16*)(base + OFF_H1IBF);
  int*   FLAGS  = (int*)(base + OFF_FLAGS);
  float* hidf   = (float*)(base + OFF_HIDF);
  float* last   = (float*)(base + OFF_LAST);
  float* logits = (float*)(base + OFF_LOGIT);

  // weight conversions to bf16
  conv_bf16_k<<<16000, 256, 0, stream>>>(Wout, WCAT, 32000, 128, 2560, 0, 1536, 0);
  conv_bf16_k<<<8000, 256, 0, stream>>>(Wout, WCAT, 32000, 64, 2560, 2048, 1536, 1024);
  conv_bf16_k<<<16000, 256, 0, stream>>>(Wout, WSEM, 32000, 128, 2560, 1024, 1024, 0);
  conv_bf16_k<<<768, 256, 0, stream>>>(Wih0, WIH0E, 3072, 64, 1536, 0, 512, 0);
  conv_bf16_k<<<1536, 256, 0, stream>>>(Wih0, WIH0S, 3072, 128, 1536, 512, 1024, 0);
  conv_bf16_k<<<1536, 256, 0, stream>>>(Whh0, WHH0B, 3072, 128, 1024, 0, 1024, 0);
  conv_bf16_k<<<1536, 256, 0, stream>>>(Wih1, WIH1B, 3072, 128, 1024, 0, 1024, 0);
  conv_bf16_k<<<1536, 256, 0, stream>>>(Whh1, WHH1B, 3072, 128, 1024, 0, 1024, 0);

  // embeddings + packed small operands + init
  gather_emb_k<<<512, 256, 0, stream>>>(seq, table, XOUT);
  pack_pad_bf16_k<<<64, 256, 0, stream>>>(syn, SYNB);
  pack_pad_bf16_k<<<64, 256, 0, stream>>>(sem, SEMB);
  init_h_k<<<64, 256, 0, stream>>>(hidden, H0IBF, H1IBF, FLAGS);

  // time-invariant bases via MFMA GEMM (M padded to 128; rows 16..127 junk)
  gemm_bt_k<2><<<dim3(1, 24), 256, 0, stream>>>(
      SYNB, 1024, WIH0S, 1024, BASE0, 3072, bih0, 3072, 1024);
  gemm_bt_k<2><<<dim3(1, 250), 256, 0, stream>>>(
      SEMB, 1024, WSEM, 1024, BASEO, 32000, bout, 32000, 1024);

  // gi0 for all t: embs @ Wih0e.T + base0
  gemm_bt_k<1><<<dim3(16, 24), 256, 0, stream>>>(
      XOUT + 1024, 1536, WIH0E, 512, GI0, 3072, BASE0, 3072, 512);

  // persistent pipelined 2-layer recurrence (129 device-wide barrier stages)
  hipFuncSetAttribute((const void*)gru_persist_k,
                      hipFuncAttributeMaxDynamicSharedMemorySize, 135168);
  gru_persist_k<<<256, 256, 135168, stream>>>(
      hidden, H0IBF, H1IBF, GI0, WHH0B, WIH1B, WHH1B, bhh0, bih1, bhh1,
      H0ALL, XOUT, hidf, last, FLAGS);

  // logits = [h1 | emb] @ WCAT.T + baseo
  gemm_bt_k<1><<<dim3(16, 250), 256, 0, stream>>>(
      XOUT, 1536, WCAT, 1536, logits, 32000, BASEO, 32000, 1536);

  // scores = log_softmax(logits) — the only writer of the scores region
  log_softmax_k<<<2048, 256, 0, stream>>>(logits, scores);
}

// Round 3
// 1967.240 us; speedup vs baseline: 2.7205x; 2.7205x over previous
//
#include <hip/hip_runtime.h>

typedef unsigned short u16;
typedef __attribute__((ext_vector_type(8))) short bf16x8;
typedef __attribute__((ext_vector_type(4))) float f32x4;

__device__ __forceinline__ float bf2f(u16 u) {
  union { unsigned u; float f; } v; v.u = ((unsigned)u) << 16; return v.f;
}
__device__ __forceinline__ u16 f2bf(float f) {
  union { float f; unsigned u; } v; v.f = f;
  unsigned r = v.u + 0x7FFFu + ((v.u >> 16) & 1u);
  return (u16)(r >> 16);
}

// device-coherent (MALL) access helpers — bypass non-coherent per-XCD L2s
__device__ __forceinline__ f32x4 ld_sc_x4(const u16* p) {
  f32x4 r;
  asm volatile("global_load_dwordx4 %0, %1, off sc0 sc1"
               : "=v"(r) : "v"(p) : "memory");
  return r;
}
__device__ __forceinline__ void st_sc_u32(u16* p, unsigned v) {
  asm volatile("global_store_dword %0, %1, off sc0 sc1"
               :: "v"(p), "v"(v) : "memory");
}
__device__ __forceinline__ void st_sc_u16(u16* p, unsigned v) {
  asm volatile("global_store_short %0, %1, off sc0 sc1"
               :: "v"(p), "v"(v) : "memory");
}
#define WAIT_VM0() asm volatile("s_waitcnt vmcnt(0)" ::: "memory")

// ---------------- scratch layout (bytes inside d_out scores region) ----------
constexpr size_t OFF_WCAT  = 0;             // bf16 [32000][1536]
constexpr size_t OFF_WSEM  = 98304000;      // bf16 [32000][1024]
constexpr size_t OFF_GI0   = 163840000;     // f32  [2048][3072]
constexpr size_t OFF_XOUT  = 189005824;     // bf16 [2048][1536]  (h1 | emb)
constexpr size_t OFF_H0ALL = 195297280;     // bf16 [128][16][1024]
constexpr size_t OFF_WIH0E = 199491584;     // bf16 [3072][512]
constexpr size_t OFF_WIH0S = 202637312;     // bf16 [3072][1024]  (syn slice)
constexpr size_t OFF_WHH0  = 208928768;     // bf16 [3072][1024]
constexpr size_t OFF_WIH1  = 215220224;     // bf16 [3072][1024]
constexpr size_t OFF_WHH1  = 221511680;     // bf16 [3072][1024]
constexpr size_t OFF_SYNB  = 227803136;     // bf16 [128][1024] (rows>=16 zero)
constexpr size_t OFF_SEMB  = 228065280;     // bf16 [128][1024]
constexpr size_t OFF_BASE0 = 228327424;     // f32  [128][3072]
constexpr size_t OFF_BASEO = 229900288;     // f32  [128][32000]
constexpr size_t OFF_H0IBF = 246284288;     // bf16 [16][1024]
constexpr size_t OFF_H1IBF = 246317056;     // bf16 [16][1024]
constexpr size_t OFF_FLAGS = 246349824;     // int [2048] padded flags (8 KB)
// real outputs
constexpr size_t OFF_HIDF  = 262144000;     // f32 [2][16][1024]
constexpr size_t OFF_LAST  = 262275072;     // f32 [16][1024]
constexpr size_t OFF_LOGIT = 262340608;     // f32 [2048][32000]

// ---------------- fp32 -> bf16 2D convert ------------------------------------
__global__ __launch_bounds__(256) void conv_bf16_k(
    const float* __restrict__ src, u16* __restrict__ dst,
    int rows, int cols8, int sld, int soff, int dld, int doff) {
  int t = blockIdx.x * 256 + threadIdx.x;
  if (t >= rows * cols8) return;
  int r = t / cols8, c = (t - r * cols8) * 8;
  const float* s = src + (size_t)r * sld + soff + c;
  float4 a = *(const float4*)s;
  float4 b = *(const float4*)(s + 4);
  bf16x8 o;
  o[0] = (short)f2bf(a.x); o[1] = (short)f2bf(a.y);
  o[2] = (short)f2bf(a.z); o[3] = (short)f2bf(a.w);
  o[4] = (short)f2bf(b.x); o[5] = (short)f2bf(b.y);
  o[6] = (short)f2bf(b.z); o[7] = (short)f2bf(b.w);
  *(bf16x8*)(dst + (size_t)r * dld + doff + c) = o;
}

// ---------------- pack [16][1024] f32 -> [128][1024] bf16, rows>=16 zeroed ---
__global__ __launch_bounds__(256) void pack_pad_bf16_k(
    const float* __restrict__ src, u16* __restrict__ dst) {
  int t = blockIdx.x * 256 + threadIdx.x;
  int row = t >> 7, c = (t & 127) * 8;
  bf16x8 o = {0, 0, 0, 0, 0, 0, 0, 0};
  if (row < 16) {
    const float* s = src + row * 1024 + c;
    float4 a = *(const float4*)s;
    float4 b = *(const float4*)(s + 4);
    o[0] = (short)f2bf(a.x); o[1] = (short)f2bf(a.y);
    o[2] = (short)f2bf(a.z); o[3] = (short)f2bf(a.w);
    o[4] = (short)f2bf(b.x); o[5] = (short)f2bf(b.y);
    o[6] = (short)f2bf(b.z); o[7] = (short)f2bf(b.w);
  }
  *(bf16x8*)(dst + (size_t)row * 1024 + c) = o;
}

// ---------------- embedding gather -> bf16 into XOUT[:,1024:1536] ------------
__global__ __launch_bounds__(256) void gather_emb_k(
    const int* __restrict__ seq, const float* __restrict__ table,
    u16* __restrict__ xout) {
  int t0 = blockIdx.x * 256 + threadIdx.x;
  int tb = t0 >> 6, c = (t0 & 63) * 8;
  int tt = tb >> 4, b = tb & 15;
  int tok = seq[b * 128 + tt];
  const float* s = table + (size_t)tok * 512 + c;
  float4 a = *(const float4*)s;
  float4 bb = *(const float4*)(s + 4);
  bf16x8 o;
  o[0] = (short)f2bf(a.x);  o[1] = (short)f2bf(a.y);
  o[2] = (short)f2bf(a.z);  o[3] = (short)f2bf(a.w);
  o[4] = (short)f2bf(bb.x); o[5] = (short)f2bf(bb.y);
  o[6] = (short)f2bf(bb.z); o[7] = (short)f2bf(bb.w);
  *(bf16x8*)(xout + (size_t)tb * 1536 + 1024 + c) = o;
}

// ---------------- init bf16 h + barrier flags --------------------------------
__global__ __launch_bounds__(256) void init_h_k(
    const float* __restrict__ hidden, u16* __restrict__ h0b,
    u16* __restrict__ h1b, int* __restrict__ flags) {
  int i = blockIdx.x * 256 + threadIdx.x;   // 16384
  h0b[i] = f2bf(hidden[i]);
  h1b[i] = f2bf(hidden[16384 + i]);
  if (i < 2048) flags[i] = 0;
}

// ---------------- stage one [16][1024] bf16 tile -> LDS (XOR swizzled) -------
__device__ __forceinline__ void stage_tile(const u16* src, int rs, u16* tile,
                                           int tid) {
  f32x4 tmp[8];
#pragma unroll
  for (int q = 0; q < 8; ++q) {
    int c = q * 256 + tid;
    int row = c >> 7, kc = c & 127;
    tmp[q] = ld_sc_x4(src + (size_t)row * rs + kc * 8);
  }
  WAIT_VM0();
#pragma unroll
  for (int q = 0; q < 8; ++q) {
    int c = q * 256 + tid;
    int row = c >> 7, kc = c & 127;
    int byte = (row * 2048 + kc * 16) ^ ((row & 7) << 4);
    *(bf16x8*)((char*)tile + byte) = *(bf16x8*)&tmp[q];
  }
}

// ---------------- persistent fence-free 2-layer GRU recurrence ---------------
// 96 blocks: 0..31 = layer0 (J=32 j each), 32..95 = layer1 (J=16 j each,
// gi1 computed inline). Sync = sc0sc1 dataflow + relaxed flags (no fences).
template <int J, bool ISL1>
__device__ __forceinline__ void gru_run(
    int lb, const float* hidden, const u16* h0i, const u16* h1i,
    const float* gi0, const u16* Wa, const u16* Wb,
    const float* bh, const float* bi,
    u16* h0all, u16* xout, float* hidf, float* last, int* flags,
    u16* A1, u16* A2, float* Clds) {
  constexpr int NJ = J / 16;      // j-tiles per gate
  constexpr int NU = 3 * NJ;      // units per part
  constexpr int NP = ISL1 ? 2 : 1;
  const int tid = threadIdx.x;
  const int wave = tid >> 6, lane = tid & 63;
  const int arow = lane & 15, aq = lane >> 4;
  const int jb = lb * J;
  const int eb = tid >> 4, jj = (tid & 15) * NJ;

  float hp[NJ], bR[NJ], bZ[NJ], bN[NJ], iR[NJ], iZ[NJ], iN[NJ];
#pragma unroll
  for (int x = 0; x < NJ; ++x) {
    int j = jb + jj + x;
    hp[x] = hidden[(ISL1 ? 16384 : 0) + eb * 1024 + j];
    bR[x] = bh[j]; bZ[x] = bh[1024 + j]; bN[x] = bh[2048 + j];
    if (ISL1) { iR[x] = bi[j]; iZ[x] = bi[1024 + j]; iN[x] = bi[2048 + j]; }
    else { iR[x] = 0.f; iZ[x] = 0.f; iN[x] = 0.f; }
  }

  int* f0 = flags;                // L0 flags, stride 16 ints
  int* f1 = flags + 64 * 16;      // L1 flags

  for (int t = 0; t < 128; ++t) {
    // ---- poll producers (relaxed agent loads, no cache maintenance) ----
    if (!ISL1) {
      if (t > 0 && tid < 32)
        while (__hip_atomic_load(f0 + tid * 16, __ATOMIC_RELAXED,
                                 __HIP_MEMORY_SCOPE_AGENT) < t) {}
    } else {
      if (tid < 32)
        while (__hip_atomic_load(f0 + tid * 16, __ATOMIC_RELAXED,
                                 __HIP_MEMORY_SCOPE_AGENT) < t + 1) {}
      if (t > 0 && tid >= 64 && tid < 128)
        while (__hip_atomic_load(f1 + (tid - 64) * 16, __ATOMIC_RELAXED,
                                 __HIP_MEMORY_SCOPE_AGENT) < t) {}
    }
    __syncthreads();

    // ---- stage A tiles (device-coherent loads -> LDS) ----
    if (!ISL1) {
      stage_tile(t ? h0all + (size_t)(t - 1) * 16384 : h0i, 1024, A1, tid);
    } else {
      stage_tile(h0all + (size_t)t * 16384, 1024, A1, tid);
      stage_tile(t ? xout + (size_t)(t - 1) * 16 * 1536 : h1i,
                 t ? 1536 : 1024, A2, tid);
    }
    __syncthreads();

    // ---- MFMA: per part, A-frags in regs, B weights streamed from L2 ----
#pragma unroll
    for (int p = 0; p < NP; ++p) {
      const u16* tile = p ? A2 : A1;
      const u16* W = p ? Wb : Wa;
      bf16x8 afr[32];
#pragma unroll
      for (int ks = 0; ks < 32; ++ks) {
        int byte = (arow * 2048 + (ks * 32 + aq * 8) * 2) ^ ((arow & 7) << 4);
        afr[ks] = *(const bf16x8*)((const char*)tile + byte);
      }
      for (int u = (wave + p) & 3; u < NU; u += 4) {
        int g = u / NJ, jt = u - g * NJ;
        const u16* bp = W + (size_t)(g * 1024 + jb + jt * 16 + arow) * 1024
                        + aq * 8;
        f32x4 a0 = {0.f, 0.f, 0.f, 0.f}, a1 = {0.f, 0.f, 0.f, 0.f};
#pragma unroll
        for (int ks = 0; ks < 32; ks += 2) {
          a0 = __builtin_amdgcn_mfma_f32_16x16x32_bf16(
              afr[ks], *(const bf16x8*)(bp + ks * 32), a0, 0, 0, 0);
          a1 = __builtin_amdgcn_mfma_f32_16x16x32_bf16(
              afr[ks + 1], *(const bf16x8*)(bp + (ks + 1) * 32), a1, 0, 0, 0);
        }
        float* cp = Clds + (p * NU + u) * 256;
        cp[(aq * 4 + 0) * 16 + arow] = a0[0] + a1[0];
        cp[(aq * 4 + 1) * 16 + arow] = a0[1] + a1[1];
        cp[(aq * 4 + 2) * 16 + arow] = a0[2] + a1[2];
        cp[(aq * 4 + 3) * 16 + arow] = a0[3] + a1[3];
      }
    }
    __syncthreads();

    // ---- epilogue: gates + h update + device-coherent store ----
    {
      float hnew[NJ];
#pragma unroll
      for (int x = 0; x < NJ; ++x) {
        int j = jj + x;
        int jt = j >> 4, col = j & 15;
        int ci = eb * 16 + col;
        float hr, hz, hn, ir, iz, inn;
        if (!ISL1) {
          hr = Clds[(0 * NJ + jt) * 256 + ci] + bR[x];
          hz = Clds[(1 * NJ + jt) * 256 + ci] + bZ[x];
          hn = Clds[(2 * NJ + jt) * 256 + ci] + bN[x];
          const float* g = gi0 + ((size_t)t * 16 + eb) * 3072 + jb + j;
          ir = g[0]; iz = g[1024]; inn = g[2048];
        } else {
          ir  = Clds[(0 * NJ + jt) * 256 + ci] + iR[x];
          iz  = Clds[(1 * NJ + jt) * 256 + ci] + iZ[x];
          inn = Clds[(2 * NJ + jt) * 256 + ci] + iN[x];
          hr  = Clds[(NU + 0 * NJ + jt) * 256 + ci] + bR[x];
          hz  = Clds[(NU + 1 * NJ + jt) * 256 + ci] + bZ[x];
          hn  = Clds[(NU + 2 * NJ + jt) * 256 + ci] + bN[x];
        }
        float r = 1.f / (1.f + __expf(-(ir + hr)));
        float z = 1.f / (1.f + __expf(-(iz + hz)));
        float n = tanhf(inn + r * hn);
        hnew[x] = (1.f - z) * n + z * hp[x];
        hp[x] = hnew[x];
      }
      if (!ISL1) {
        unsigned pk = (unsigned)f2bf(hnew[0]) | ((unsigned)f2bf(hnew[1]) << 16);
        st_sc_u32(h0all + ((size_t)t * 16 + eb) * 1024 + jb + jj, pk);
        if (t == 127) {
          hidf[eb * 1024 + jb + jj] = hnew[0];
          hidf[eb * 1024 + jb + jj + 1] = hnew[1];
        }
      } else {
        st_sc_u16(xout + ((size_t)t * 16 + eb) * 1536 + jb + jj,
                  (unsigned)f2bf(hnew[0]));
        if (t == 127) {
          hidf[16384 + eb * 1024 + jb + jj] = hnew[0];
          last[eb * 1024 + jb + jj] = hnew[0];
        }
      }
      WAIT_VM0();
    }
    __syncthreads();
    if (tid == 0)
      __hip_atomic_store((ISL1 ? f1 + lb * 16 : f0 + lb * 16), t + 1,
                         __ATOMIC_RELAXED, __HIP_MEMORY_SCOPE_AGENT);
  }
}

__global__ __launch_bounds__(256, 1) void gru_persist2_k(
    const float* __restrict__ hidden, const u16* __restrict__ h0i,
    const u16* __restrict__ h1i, const float* __restrict__ gi0,
    const u16* __restrict__ Whh0, const u16* __restrict__ Wih1,
    const u16* __restrict__ Whh1, const float* __restrict__ bhh0,
    const float* __restrict__ bih1, const float* __restrict__ bhh1,
    u16* __restrict__ h0all, u16* __restrict__ xout,
    float* __restrict__ hidf, float* __restrict__ last,
    int* __restrict__ flags) {
  extern __shared__ u16 lds[];
  u16* A1 = lds;
  u16* A2 = lds + 16384;
  float* Clds = (float*)(lds + 32768);
  const int bid = blockIdx.x;
  if (bid < 32)
    gru_run<32, false>(bid, hidden, h0i, h1i, gi0, Whh0, nullptr, bhh0,
                       nullptr, h0all, xout, hidf, last, flags, A1, A2, Clds);
  else
    gru_run<16, true>(bid - 32, hidden, h0i, h1i, gi0, Wih1, Whh1, bhh1,
                      bih1, h0all, xout, hidf, last, flags, A1, A2, Clds);
}

// ---------------- bf16 MFMA GEMM: C[M,N] = A[M,K] @ B[N,K].T (+ add) ---------
template <int MODE>
__global__ __launch_bounds__(256) void gemm_bt_k(
    const u16* __restrict__ A, int lda, const u16* __restrict__ Bw, int ldb,
    float* __restrict__ C, int ldc, const float* __restrict__ add,
    int N, int K) {
  __shared__ u16 Asm_[128 * 32];
  __shared__ u16 Bsm_[128 * 32];
  const int m0 = blockIdx.x * 128, n0 = blockIdx.y * 128;
  const int tid = threadIdx.x, wave = tid >> 6, lane = tid & 63;
  const int wm = (wave >> 1) * 64, wn = (wave & 1) * 64;
  const int lrow = lane & 15, lk = (lane >> 4) * 8;
  f32x4 acc[4][4] = {};
  for (int k0 = 0; k0 < K; k0 += 32) {
    __syncthreads();
#pragma unroll
    for (int q = 0; q < 2; ++q) {
      int c = (wave * 2 + q) * 64 + lane;
      int row = c >> 2, seg = c & 3;
      const u16* src = A + (size_t)(m0 + row) * lda + k0 + seg * 8;
      u16* dst = Asm_ + (wave * 2 + q) * 512;
      __builtin_amdgcn_global_load_lds(
          (const __attribute__((address_space(1))) void*)src,
          (__attribute__((address_space(3))) void*)dst, 16, 0, 0);
    }
#pragma unroll
    for (int q = 0; q < 2; ++q) {
      int c = (wave * 2 + q) * 64 + lane;
      int row = c >> 2, seg = c & 3;
      const u16* src = Bw + (size_t)(n0 + row) * ldb + k0 + seg * 8;
      u16* dst = Bsm_ + (wave * 2 + q) * 512;
      __builtin_amdgcn_global_load_lds(
          (const __attribute__((address_space(1))) void*)src,
          (__attribute__((address_space(3))) void*)dst, 16, 0, 0);
    }
    asm volatile("s_waitcnt vmcnt(0)" ::: "memory");
    __syncthreads();
    bf16x8 af[4], bfr[4];
#pragma unroll
    for (int i = 0; i < 4; ++i) {
      af[i]  = *(const bf16x8*)(Asm_ + (wm + i * 16 + lrow) * 32 + lk);
      bfr[i] = *(const bf16x8*)(Bsm_ + (wn + i * 16 + lrow) * 32 + lk);
    }
#pragma unroll
    for (int i = 0; i < 4; ++i)
#pragma unroll
      for (int j = 0; j < 4; ++j)
        acc[i][j] = __builtin_amdgcn_mfma_f32_16x16x32_bf16(
            af[i], bfr[j], acc[i][j], 0, 0, 0);
  }
  const int lr4 = (lane >> 4) * 4;
#pragma unroll
  for (int i = 0; i < 4; ++i) {
#pragma unroll
    for (int j = 0; j < 4; ++j) {
      int gc = n0 + wn + j * 16 + lrow;
#pragma unroll
      for (int r = 0; r < 4; ++r) {
        int gr = m0 + wm + i * 16 + lr4 + r;
        float v = acc[i][j][r];
        if (MODE == 1) v += add[(gr & 15) * N + gc];
        else if (MODE == 2) v += add[gc];
        C[(size_t)gr * ldc + gc] = v;
      }
    }
  }
}

// ---------------- row-wise log_softmax (rows of 32000) -----------------------
__global__ __launch_bounds__(256) void log_softmax_k(
    const float* __restrict__ logits, float* __restrict__ scores) {
  int row = blockIdx.x;
  const float* x = logits + (size_t)row * 32000;
  float* y = scores + (size_t)row * 32000;
  __shared__ float red[8];
  int tid = threadIdx.x;
  float m = -3.4e38f;
  for (int idx = tid * 4; idx < 32000; idx += 1024) {
    float4 v = *(const float4*)(x + idx);
    m = fmaxf(m, fmaxf(fmaxf(v.x, v.y), fmaxf(v.z, v.w)));
  }
  for (int off = 32; off; off >>= 1) m = fmaxf(m, __shfl_xor(m, off));
  if ((tid & 63) == 0) red[tid >> 6] = m;
  __syncthreads();
  m = fmaxf(fmaxf(red[0], red[1]), fmaxf(red[2], red[3]));
  float s = 0.f;
  for (int idx = tid * 4; idx < 32000; idx += 1024) {
    float4 v = *(const float4*)(x + idx);
    s += __expf(v.x - m) + __expf(v.y - m) + __expf(v.z - m) + __expf(v.w - m);
  }
  for (int off = 32; off; off >>= 1) s += __shfl_xor(s, off);
  if ((tid & 63) == 0) red[4 + (tid >> 6)] = s;
  __syncthreads();
  s = red[4] + red[5] + red[6] + red[7];
  float lse = m + logf(s);
  for (int idx = tid * 4; idx < 32000; idx += 1024) {
    float4 v = *(const float4*)(x + idx);
    float4 o;
    o.x = v.x - lse; o.y = v.y - lse; o.z = v.z - lse; o.w = v.w - lse;
    *(float4*)(y + idx) = o;
  }
}

// =============================================================================
extern "C" void kernel_launch(void* const* d_in, const int* in_sizes, int n_in,
                              void* d_out, int out_size, void* d_ws,
                              size_t ws_size, hipStream_t stream) {
  const int*   seq    = (const int*)d_in[0];
  const float* sem    = (const float*)d_in[2];
  const float* syn    = (const float*)d_in[3];
  const float* hidden = (const float*)d_in[4];
  const float* table  = (const float*)d_in[5];
  const float* Wih0   = (const float*)d_in[6];
  const float* Whh0   = (const float*)d_in[7];
  const float* bih0   = (const float*)d_in[8];
  const float* bhh0   = (const float*)d_in[9];
  const float* Wih1   = (const float*)d_in[10];
  const float* Whh1   = (const float*)d_in[11];
  const float* bih1   = (const float*)d_in[12];
  const float* bhh1   = (const float*)d_in[13];
  const float* Wout   = (const float*)d_in[14];
  const float* bout   = (const float*)d_in[15];

  char* base = (char*)d_out;
  float* scores = (float*)base;
  u16*   WCAT   = (u16*)(base + OFF_WCAT);
  u16*   WSEM   = (u16*)(base + OFF_WSEM);
  float* GI0    = (float*)(base + OFF_GI0);
  u16*   XOUT   = (u16*)(base + OFF_XOUT);
  u16*   H0ALL  = (u16*)(base + OFF_H0ALL);
  u16*   WIH0E  = (u16*)(base + OFF_WIH0E);
  u16*   WIH0S  = (u16*)(base + OFF_WIH0S);
  u16*   WHH0B  = (u16*)(base + OFF_WHH0);
  u16*   WIH1B  = (u16*)(base + OFF_WIH1);
  u16*   WHH1B  = (u16*)(base + OFF_WHH1);
  u16*   SYNB   = (u16*)(base + OFF_SYNB);
  u16*   SEMB   = (u16*)(base + OFF_SEMB);
  float* BASE0  = (float*)(base + OFF_BASE0);
  float* BASEO  = (float*)(base + OFF_BASEO);
  u16*   H0IBF  = (u16*)(base + OFF_H0IBF);
  u16*   H1IBF  = (u16*)(base + OFF_H1IBF);
  int*   FLAGS  = (int*)(base + OFF_FLAGS);
  float* hidf   = (float*)(base + OFF_HIDF);
  float* last   = (float*)(base + OFF_LAST);
  float* logits = (float*)(base + OFF_LOGIT);

  // weight conversions to bf16
  conv_bf16_k<<<16000, 256, 0, stream>>>(Wout, WCAT, 32000, 128, 2560, 0, 1536, 0);
  conv_bf16_k<<<8000, 256, 0, stream>>>(Wout, WCAT, 32000, 64, 2560, 2048, 1536, 1024);
  conv_bf16_k<<<16000, 256, 0, stream>>>(Wout, WSEM, 32000, 128, 2560, 1024, 1024, 0);
  conv_bf16_k<<<768, 256, 0, stream>>>(Wih0, WIH0E, 3072, 64, 1536, 0, 512, 0);
  conv_bf16_k<<<1536, 256, 0, stream>>>(Wih0, WIH0S, 3072, 128, 1536, 512, 1024, 0);
  conv_bf16_k<<<1536, 256, 0, stream>>>(Whh0, WHH0B, 3072, 128, 1024, 0, 1024, 0);
  conv_bf16_k<<<1536, 256, 0, stream>>>(Wih1, WIH1B, 3072, 128, 1024, 0, 1024, 0);
  conv_bf16_k<<<1536, 256, 0, stream>>>(Whh1, WHH1B, 3072, 128, 1024, 0, 1024, 0);

  // embeddings + packed small operands + init
  gather_emb_k<<<512, 256, 0, stream>>>(seq, table, XOUT);
  pack_pad_bf16_k<<<64, 256, 0, stream>>>(syn, SYNB);
  pack_pad_bf16_k<<<64, 256, 0, stream>>>(sem, SEMB);
  init_h_k<<<64, 256, 0, stream>>>(hidden, H0IBF, H1IBF, FLAGS);

  // time-invariant bases via MFMA GEMM (M padded to 128; rows 16..127 junk)
  gemm_bt_k<2><<<dim3(1, 24), 256, 0, stream>>>(
      SYNB, 1024, WIH0S, 1024, BASE0, 3072, bih0, 3072, 1024);
  gemm_bt_k<2><<<dim3(1, 250), 256, 0, stream>>>(
      SEMB, 1024, WSEM, 1024, BASEO, 32000, bout, 32000, 1024);

  // gi0 for all t: embs @ Wih0e.T + base0
  gemm_bt_k<1><<<dim3(16, 24), 256, 0, stream>>>(
      XOUT + 1024, 1536, WIH0E, 512, GI0, 3072, BASE0, 3072, 512);

  // persistent fence-free recurrence (96 blocks, dataflow sync via MALL)
  hipFuncSetAttribute((const void*)gru_persist2_k,
                      hipFuncAttributeMaxDynamicSharedMemorySize, 71680);
  gru_persist2_k<<<96, 256, 71680, stream>>>(
      hidden, H0IBF, H1IBF, GI0, WHH0B, WIH1B, WHH1B, bhh0, bih1, bhh1,
      H0ALL, XOUT, hidf, last, FLAGS);

  // logits = [h1 | emb] @ WCAT.T + baseo
  gemm_bt_k<1><<<dim3(16, 250), 256, 0, stream>>>(
      XOUT, 1536, WCAT, 1536, logits, 32000, BASEO, 32000, 1536);

  // scores = log_softmax(logits) — the only writer of the scores region
  log_softmax_k<<<2048, 256, 0, stream>>>(logits, scores);
}

// Round 4
// 1276.922 us; speedup vs baseline: 4.1913x; 1.5406x over previous
//
#include <hip/hip_runtime.h>

typedef unsigned short u16;
typedef __attribute__((ext_vector_type(8))) short bf16x8;
typedef __attribute__((ext_vector_type(4))) float f32x4;

__device__ __forceinline__ float bf2f(u16 u) {
  union { unsigned u; float f; } v; v.u = ((unsigned)u) << 16; return v.f;
}
__device__ __forceinline__ u16 f2bf(float f) {
  union { float f; unsigned u; } v; v.f = f;
  unsigned r = v.u + 0x7FFFu + ((v.u >> 16) & 1u);
  return (u16)(r >> 16);
}

// device-coherent (MALL) access helpers — bypass non-coherent per-XCD L2s
__device__ __forceinline__ f32x4 ld_sc_x4(const u16* p) {
  f32x4 r;
  asm volatile("global_load_dwordx4 %0, %1, off sc0 sc1"
               : "=v"(r) : "v"(p) : "memory");
  return r;
}
__device__ __forceinline__ float ld_sc_f32(const float* p) {
  float r;
  asm volatile("global_load_dword %0, %1, off sc0 sc1"
               : "=v"(r) : "v"(p) : "memory");
  return r;
}
__device__ __forceinline__ void st_sc_u16(u16* p, unsigned v) {
  asm volatile("global_store_short %0, %1, off sc0 sc1"
               :: "v"(p), "v"(v) : "memory");
}
__device__ __forceinline__ void st_sc_f32(float* p, float v) {
  asm volatile("global_store_dword %0, %1, off sc0 sc1"
               :: "v"(p), "v"(v) : "memory");
}
#define WAIT_VM0() asm volatile("s_waitcnt vmcnt(0)" ::: "memory")

__device__ __forceinline__ int ld_flag(const int* p) {
  return __hip_atomic_load(p, __ATOMIC_RELAXED, __HIP_MEMORY_SCOPE_AGENT);
}
__device__ __forceinline__ void st_flag(int* p, int v) {
  __hip_atomic_store(p, v, __ATOMIC_RELAXED, __HIP_MEMORY_SCOPE_AGENT);
}

// ---------------- scratch layout (bytes inside d_out scores region) ----------
constexpr size_t OFF_WCAT  = 0;             // bf16 [32000][1536]
constexpr size_t OFF_WSEM  = 98304000;      // bf16 [32000][1024] (later: PART)
constexpr size_t OFF_PART  = 98304000;      // f32 [128][64][768] gi1 partials
constexpr size_t OFF_H1ALL = 130000000;     // bf16 [128][16][1024]
constexpr size_t OFF_GI0   = 163840000;     // f32  [2048][3072]
constexpr size_t OFF_XOUT  = 189005824;     // bf16 [2048][1536]  (h1 | emb)
constexpr size_t OFF_H0ALL = 195297280;     // bf16 [128][16][1024]
constexpr size_t OFF_WIH0E = 199491584;     // bf16 [3072][512]
constexpr size_t OFF_WIH0S = 202637312;     // bf16 [3072][1024]  (syn slice)
constexpr size_t OFF_WHH0  = 208928768;     // bf16 [3072][1024]
constexpr size_t OFF_WIH1  = 215220224;     // bf16 [3072][1024]
constexpr size_t OFF_WHH1  = 221511680;     // bf16 [3072][1024]
constexpr size_t OFF_SYNB  = 227803136;     // bf16 [128][1024] (rows>=16 zero)
constexpr size_t OFF_SEMB  = 228065280;     // bf16 [128][1024]
constexpr size_t OFF_BASE0 = 228327424;     // f32  [128][3072]
constexpr size_t OFF_BASEO = 229900288;     // f32  [128][32000]
constexpr size_t OFF_H0IBF = 246284288;     // bf16 [16][1024]
constexpr size_t OFF_H1IBF = 246317056;     // bf16 [16][1024]
constexpr size_t OFF_FLAGS = 246349824;     // int [4096] flags (16 KB)
// real outputs
constexpr size_t OFF_HIDF  = 262144000;     // f32 [2][16][1024]
constexpr size_t OFF_LAST  = 262275072;     // f32 [16][1024]
constexpr size_t OFF_LOGIT = 262340608;     // f32 [2048][32000]

// ---------------- fp32 -> bf16 2D convert ------------------------------------
__global__ __launch_bounds__(256) void conv_bf16_k(
    const float* __restrict__ src, u16* __restrict__ dst,
    int rows, int cols8, int sld, int soff, int dld, int doff) {
  int t = blockIdx.x * 256 + threadIdx.x;
  if (t >= rows * cols8) return;
  int r = t / cols8, c = (t - r * cols8) * 8;
  const float* s = src + (size_t)r * sld + soff + c;
  float4 a = *(const float4*)s;
  float4 b = *(const float4*)(s + 4);
  bf16x8 o;
  o[0] = (short)f2bf(a.x); o[1] = (short)f2bf(a.y);
  o[2] = (short)f2bf(a.z); o[3] = (short)f2bf(a.w);
  o[4] = (short)f2bf(b.x); o[5] = (short)f2bf(b.y);
  o[6] = (short)f2bf(b.z); o[7] = (short)f2bf(b.w);
  *(bf16x8*)(dst + (size_t)r * dld + doff + c) = o;
}

// ---------------- pack [16][1024] f32 -> [128][1024] bf16, rows>=16 zeroed ---
__global__ __launch_bounds__(256) void pack_pad_bf16_k(
    const float* __restrict__ src, u16* __restrict__ dst) {
  int t = blockIdx.x * 256 + threadIdx.x;
  int row = t >> 7, c = (t & 127) * 8;
  bf16x8 o = {0, 0, 0, 0, 0, 0, 0, 0};
  if (row < 16) {
    const float* s = src + row * 1024 + c;
    float4 a = *(const float4*)s;
    float4 b = *(const float4*)(s + 4);
    o[0] = (short)f2bf(a.x); o[1] = (short)f2bf(a.y);
    o[2] = (short)f2bf(a.z); o[3] = (short)f2bf(a.w);
    o[4] = (short)f2bf(b.x); o[5] = (short)f2bf(b.y);
    o[6] = (short)f2bf(b.z); o[7] = (short)f2bf(b.w);
  }
  *(bf16x8*)(dst + (size_t)row * 1024 + c) = o;
}

// ---------------- embedding gather -> bf16 into XOUT[:,1024:1536] ------------
__global__ __launch_bounds__(256) void gather_emb_k(
    const int* __restrict__ seq, const float* __restrict__ table,
    u16* __restrict__ xout) {
  int t0 = blockIdx.x * 256 + threadIdx.x;
  int tb = t0 >> 6, c = (t0 & 63) * 8;
  int tt = tb >> 4, b = tb & 15;
  int tok = seq[b * 128 + tt];
  const float* s = table + (size_t)tok * 512 + c;
  float4 a = *(const float4*)s;
  float4 bb = *(const float4*)(s + 4);
  bf16x8 o;
  o[0] = (short)f2bf(a.x);  o[1] = (short)f2bf(a.y);
  o[2] = (short)f2bf(a.z);  o[3] = (short)f2bf(a.w);
  o[4] = (short)f2bf(bb.x); o[5] = (short)f2bf(bb.y);
  o[6] = (short)f2bf(bb.z); o[7] = (short)f2bf(bb.w);
  *(bf16x8*)(xout + (size_t)tb * 1536 + 1024 + c) = o;
}

// ---------------- init bf16 h + barrier flags --------------------------------
__global__ __launch_bounds__(256) void init_h_k(
    const float* __restrict__ hidden, u16* __restrict__ h0b,
    u16* __restrict__ h1b, int* __restrict__ flags) {
  int i = blockIdx.x * 256 + threadIdx.x;   // 16384
  h0b[i] = f2bf(hidden[i]);
  h1b[i] = f2bf(hidden[16384 + i]);
  if (i < 4096) flags[i] = 0;
}

// ---------------- stage one [16][1024] bf16 tile -> LDS (XOR swizzled) -------
__device__ __forceinline__ void stage_tile(const u16* src, char* tile,
                                           int tid) {
  f32x4 tmp[8];
#pragma unroll
  for (int q = 0; q < 8; ++q) {
    int c = q * 256 + tid;
    int row = c >> 7, kc = c & 127;
    tmp[q] = ld_sc_x4(src + (size_t)row * 1024 + kc * 8);
  }
  WAIT_VM0();
#pragma unroll
  for (int q = 0; q < 8; ++q) {
    int c = q * 256 + tid;
    int row = c >> 7, kc = c & 127;
    int byte = (row * 2048 + kc * 16) ^ ((row & 7) << 4);
    *(bf16x8*)(tile + byte) = *(bf16x8*)&tmp[q];
  }
}

// ---------------- persistent 2-layer GRU, LDS-resident weights ---------------
// 192 blocks (1/CU): 0..63 L0 (16 j each, Whh0 slice in LDS);
// 64..127 L1-ih (Wih1 slice; computes gi1 partials, one stage ahead);
// 128..191 L1-hh (Whh1 slice; owns h1 state + epilogue).
// LDS: [0,98304) W slice (swizzled), [98304,131072) A tile, [131072,143360) C.
__global__ __launch_bounds__(256, 1) void gru_persist3_k(
    const float* __restrict__ hidden, const u16* __restrict__ h0i,
    const u16* __restrict__ h1i, const float* __restrict__ gi0,
    const u16* __restrict__ Whh0, const u16* __restrict__ Wih1,
    const u16* __restrict__ Whh1, const float* __restrict__ bhh0,
    const float* __restrict__ bih1, const float* __restrict__ bhh1,
    u16* __restrict__ h0all, u16* __restrict__ h1all, u16* __restrict__ xout,
    float* __restrict__ part, float* __restrict__ hidf,
    float* __restrict__ last, int* __restrict__ flags) {
  extern __shared__ char ldsb[];
  char* Ab = ldsb + 98304;
  float* Cl = (float*)(ldsb + 131072);
  const int tid = threadIdx.x, bid = blockIdx.x;
  const int wave = tid >> 6, lane = tid & 63;
  const int role = bid >> 6, lb = bid & 63, jb = lb * 16;
  int* f0 = flags, *fih = flags + 1024, *f1 = flags + 2048;

  // ---- stage weight slice into LDS (once) ----
  const u16* Wsrc = role == 0 ? Whh0 : (role == 1 ? Wih1 : Whh1);
  for (int idx = tid; idx < 48 * 128; idx += 256) {
    int row = idx >> 7, c = idx & 127;
    int g = row >> 4, jj = row & 15;
    const u16* src = Wsrc + (size_t)(g * 1024 + jb + jj) * 1024 + c * 8;
    int byte = (row * 2048 + c * 16) ^ ((row & 7) << 4);
    *(bf16x8*)(ldsb + byte) = *(const bf16x8*)src;
  }

  // ---- per-thread epilogue identity: b = tid>>4, jj = tid&15, one j each ----
  const int eb = tid >> 4, jj = tid & 15, j = jb + jj;
  float hp = 0.f, bR = 0.f, bZ = 0.f, bN = 0.f, iR = 0.f, iZ = 0.f, iN = 0.f;
  if (role == 0) {
    hp = hidden[eb * 1024 + j];
    bR = bhh0[j]; bZ = bhh0[1024 + j]; bN = bhh0[2048 + j];
  } else if (role == 2) {
    hp = hidden[16384 + eb * 1024 + j];
    bR = bhh1[j]; bZ = bhh1[1024 + j]; bN = bhh1[2048 + j];
    iR = bih1[j]; iZ = bih1[1024 + j]; iN = bih1[2048 + j];
  }
  __syncthreads();

  const int arow = lane & 15, aq = lane >> 4;
  for (int t = 0; t < 128; ++t) {
    // ---- 1. poll producer flags (lanes 0-63 of wave 0) ----
    if (role == 0) {
      if (t > 0 && tid < 64)
        while (ld_flag(f0 + tid * 16) < t) __builtin_amdgcn_s_sleep(1);
    } else if (role == 1) {
      if (tid < 64)
        while (ld_flag(f0 + tid * 16) < t + 1) __builtin_amdgcn_s_sleep(1);
    } else {
      if (t > 0 && tid < 64)
        while (ld_flag(f1 + tid * 16) < t) __builtin_amdgcn_s_sleep(1);
    }
    __syncthreads();

    // ---- 2. stage A tile (device-coherent loads -> swizzled LDS) ----
    const u16* asrc;
    if (role == 0)      asrc = t ? h0all + (size_t)(t - 1) * 16384 : h0i;
    else if (role == 1) asrc = h0all + (size_t)t * 16384;
    else                asrc = t ? h1all + (size_t)(t - 1) * 16384 : h1i;
    stage_tile(asrc, Ab, tid);
    __syncthreads();

    // ---- 3. MFMA: 3 gate chains (ILP), A+B from LDS; wave w does ks=w+4i ----
    {
      f32x4 a0 = {0.f, 0.f, 0.f, 0.f}, a1 = a0, a2 = a0;
#pragma unroll
      for (int i = 0; i < 8; ++i) {
        int ks = wave + i * 4;
        int abyte = (arow * 2048 + ks * 64 + aq * 16) ^ ((arow & 7) << 4);
        bf16x8 af = *(const bf16x8*)(Ab + abyte);
        int r0 = arow, r1 = 16 + arow, r2 = 32 + arow;
        bf16x8 b0 = *(const bf16x8*)(
            ldsb + ((r0 * 2048 + ks * 64 + aq * 16) ^ ((r0 & 7) << 4)));
        bf16x8 b1 = *(const bf16x8*)(
            ldsb + ((r1 * 2048 + ks * 64 + aq * 16) ^ ((r1 & 7) << 4)));
        bf16x8 b2 = *(const bf16x8*)(
            ldsb + ((r2 * 2048 + ks * 64 + aq * 16) ^ ((r2 & 7) << 4)));
        a0 = __builtin_amdgcn_mfma_f32_16x16x32_bf16(af, b0, a0, 0, 0, 0);
        a1 = __builtin_amdgcn_mfma_f32_16x16x32_bf16(af, b1, a1, 0, 0, 0);
        a2 = __builtin_amdgcn_mfma_f32_16x16x32_bf16(af, b2, a2, 0, 0, 0);
      }
#pragma unroll
      for (int r = 0; r < 4; ++r) {
        int ci = (aq * 4 + r) * 16 + arow;
        Cl[(0 * 4 + wave) * 256 + ci] = a0[r];
        Cl[(1 * 4 + wave) * 256 + ci] = a1[r];
        Cl[(2 * 4 + wave) * 256 + ci] = a2[r];
      }
    }
    // hh: wait for this stage's gi1 partial flag while C settles
    if (role == 2 && tid == 0)
      while (ld_flag(fih + lb * 16) < t + 1) __builtin_amdgcn_s_sleep(1);
    __syncthreads();

    // ---- 4. epilogue ----
    {
      int ci = eb * 16 + jj;
      float s0 = Cl[(0 * 4 + 0) * 256 + ci] + Cl[(0 * 4 + 1) * 256 + ci] +
                 Cl[(0 * 4 + 2) * 256 + ci] + Cl[(0 * 4 + 3) * 256 + ci];
      float s1 = Cl[(1 * 4 + 0) * 256 + ci] + Cl[(1 * 4 + 1) * 256 + ci] +
                 Cl[(1 * 4 + 2) * 256 + ci] + Cl[(1 * 4 + 3) * 256 + ci];
      float s2 = Cl[(2 * 4 + 0) * 256 + ci] + Cl[(2 * 4 + 1) * 256 + ci] +
                 Cl[(2 * 4 + 2) * 256 + ci] + Cl[(2 * 4 + 3) * 256 + ci];
      if (role == 1) {
        float* pp = part + ((size_t)t * 64 + lb) * 768 + eb * 16 + jj;
        st_sc_f32(pp, s0);
        st_sc_f32(pp + 256, s1);
        st_sc_f32(pp + 512, s2);
        WAIT_VM0();
      } else {
        float ir, iz, inn;
        if (role == 0) {
          const float* g = gi0 + ((size_t)t * 16 + eb) * 3072 + j;
          ir = g[0]; iz = g[1024]; inn = g[2048];
        } else {
          const float* pp = part + ((size_t)t * 64 + lb) * 768 + eb * 16 + jj;
          float p0 = ld_sc_f32(pp), p1 = ld_sc_f32(pp + 256),
                p2 = ld_sc_f32(pp + 512);
          WAIT_VM0();
          ir = p0 + iR; iz = p1 + iZ; inn = p2 + iN;
        }
        float r = 1.f / (1.f + __expf(-(ir + s0 + bR)));
        float z = 1.f / (1.f + __expf(-(iz + s1 + bZ)));
        float n = tanhf(inn + r * (s2 + bN));
        float hnew = (1.f - z) * n + z * hp;
        hp = hnew;
        u16 hb = f2bf(hnew);
        if (role == 0) {
          st_sc_u16(h0all + ((size_t)t * 16 + eb) * 1024 + j, (unsigned)hb);
          if (t == 127) hidf[eb * 1024 + j] = hnew;
        } else {
          st_sc_u16(h1all + ((size_t)t * 16 + eb) * 1024 + j, (unsigned)hb);
          xout[((size_t)t * 16 + eb) * 1536 + j] = hb;  // plain store
          if (t == 127) {
            hidf[16384 + eb * 1024 + j] = hnew;
            last[eb * 1024 + j] = hnew;
          }
        }
        WAIT_VM0();
      }
    }
    __syncthreads();
    // ---- 5. publish flag ----
    if (tid == 0) {
      if (role == 0)      st_flag(f0 + lb * 16, t + 1);
      else if (role == 1) st_flag(fih + lb * 16, t + 1);
      else                st_flag(f1 + lb * 16, t + 1);
    }
  }
}

// ---------------- bf16 MFMA GEMM: C[M,N] = A[M,K] @ B[N,K].T (+ add) ---------
template <int MODE>
__global__ __launch_bounds__(256) void gemm_bt_k(
    const u16* __restrict__ A, int lda, const u16* __restrict__ Bw, int ldb,
    float* __restrict__ C, int ldc, const float* __restrict__ add,
    int N, int K) {
  __shared__ u16 Asm_[128 * 32];
  __shared__ u16 Bsm_[128 * 32];
  const int m0 = blockIdx.x * 128, n0 = blockIdx.y * 128;
  const int tid = threadIdx.x, wave = tid >> 6, lane = tid & 63;
  const int wm = (wave >> 1) * 64, wn = (wave & 1) * 64;
  const int lrow = lane & 15, lk = (lane >> 4) * 8;
  f32x4 acc[4][4] = {};
  for (int k0 = 0; k0 < K; k0 += 32) {
    __syncthreads();
#pragma unroll
    for (int q = 0; q < 2; ++q) {
      int c = (wave * 2 + q) * 64 + lane;
      int row = c >> 2, seg = c & 3;
      const u16* src = A + (size_t)(m0 + row) * lda + k0 + seg * 8;
      u16* dst = Asm_ + (wave * 2 + q) * 512;
      __builtin_amdgcn_global_load_lds(
          (const __attribute__((address_space(1))) void*)src,
          (__attribute__((address_space(3))) void*)dst, 16, 0, 0);
    }
#pragma unroll
    for (int q = 0; q < 2; ++q) {
      int c = (wave * 2 + q) * 64 + lane;
      int row = c >> 2, seg = c & 3;
      const u16* src = Bw + (size_t)(n0 + row) * ldb + k0 + seg * 8;
      u16* dst = Bsm_ + (wave * 2 + q) * 512;
      __builtin_amdgcn_global_load_lds(
          (const __attribute__((address_space(1))) void*)src,
          (__attribute__((address_space(3))) void*)dst, 16, 0, 0);
    }
    asm volatile("s_waitcnt vmcnt(0)" ::: "memory");
    __syncthreads();
    bf16x8 af[4], bfr[4];
#pragma unroll
    for (int i = 0; i < 4; ++i) {
      af[i]  = *(const bf16x8*)(Asm_ + (wm + i * 16 + lrow) * 32 + lk);
      bfr[i] = *(const bf16x8*)(Bsm_ + (wn + i * 16 + lrow) * 32 + lk);
    }
#pragma unroll
    for (int i = 0; i < 4; ++i)
#pragma unroll
      for (int j = 0; j < 4; ++j)
        acc[i][j] = __builtin_amdgcn_mfma_f32_16x16x32_bf16(
            af[i], bfr[j], acc[i][j], 0, 0, 0);
  }
  const int lr4 = (lane >> 4) * 4;
#pragma unroll
  for (int i = 0; i < 4; ++i) {
#pragma unroll
    for (int j = 0; j < 4; ++j) {
      int gc = n0 + wn + j * 16 + lrow;
#pragma unroll
      for (int r = 0; r < 4; ++r) {
        int gr = m0 + wm + i * 16 + lr4 + r;
        float v = acc[i][j][r];
        if (MODE == 1) v += add[(gr & 15) * N + gc];
        else if (MODE == 2) v += add[gc];
        C[(size_t)gr * ldc + gc] = v;
      }
    }
  }
}

// ---------------- row-wise log_softmax (rows of 32000) -----------------------
__global__ __launch_bounds__(256) void log_softmax_k(
    const float* __restrict__ logits, float* __restrict__ scores) {
  int row = blockIdx.x;
  const float* x = logits + (size_t)row * 32000;
  float* y = scores + (size_t)row * 32000;
  __shared__ float red[8];
  int tid = threadIdx.x;
  float m = -3.4e38f;
  for (int idx = tid * 4; idx < 32000; idx += 1024) {
    float4 v = *(const float4*)(x + idx);
    m = fmaxf(m, fmaxf(fmaxf(v.x, v.y), fmaxf(v.z, v.w)));
  }
  for (int off = 32; off; off >>= 1) m = fmaxf(m, __shfl_xor(m, off));
  if ((tid & 63) == 0) red[tid >> 6] = m;
  __syncthreads();
  m = fmaxf(fmaxf(red[0], red[1]), fmaxf(red[2], red[3]));
  float s = 0.f;
  for (int idx = tid * 4; idx < 32000; idx += 1024) {
    float4 v = *(const float4*)(x + idx);
    s += __expf(v.x - m) + __expf(v.y - m) + __expf(v.z - m) + __expf(v.w - m);
  }
  for (int off = 32; off; off >>= 1) s += __shfl_xor(s, off);
  if ((tid & 63) == 0) red[4 + (tid >> 6)] = s;
  __syncthreads();
  s = red[4] + red[5] + red[6] + red[7];
  float lse = m + logf(s);
  for (int idx = tid * 4; idx < 32000; idx += 1024) {
    float4 v = *(const float4*)(x + idx);
    float4 o;
    o.x = v.x - lse; o.y = v.y - lse; o.z = v.z - lse; o.w = v.w - lse;
    *(float4*)(y + idx) = o;
  }
}

// =============================================================================
extern "C" void kernel_launch(void* const* d_in, const int* in_sizes, int n_in,
                              void* d_out, int out_size, void* d_ws,
                              size_t ws_size, hipStream_t stream) {
  const int*   seq    = (const int*)d_in[0];
  const float* sem    = (const float*)d_in[2];
  const float* syn    = (const float*)d_in[3];
  const float* hidden = (const float*)d_in[4];
  const float* table  = (const float*)d_in[5];
  const float* Wih0   = (const float*)d_in[6];
  const float* Whh0   = (const float*)d_in[7];
  const float* bih0   = (const float*)d_in[8];
  const float* bhh0   = (const float*)d_in[9];
  const float* Wih1   = (const float*)d_in[10];
  const float* Whh1   = (const float*)d_in[11];
  const float* bih1   = (const float*)d_in[12];
  const float* bhh1   = (const float*)d_in[13];
  const float* Wout   = (const float*)d_in[14];
  const float* bout   = (const float*)d_in[15];

  char* base = (char*)d_out;
  float* scores = (float*)base;
  u16*   WCAT   = (u16*)(base + OFF_WCAT);
  u16*   WSEM   = (u16*)(base + OFF_WSEM);
  float* PART   = (float*)(base + OFF_PART);
  u16*   H1ALL  = (u16*)(base + OFF_H1ALL);
  float* GI0    = (float*)(base + OFF_GI0);
  u16*   XOUT   = (u16*)(base + OFF_XOUT);
  u16*   H0ALL  = (u16*)(base + OFF_H0ALL);
  u16*   WIH0E  = (u16*)(base + OFF_WIH0E);
  u16*   WIH0S  = (u16*)(base + OFF_WIH0S);
  u16*   WHH0B  = (u16*)(base + OFF_WHH0);
  u16*   WIH1B  = (u16*)(base + OFF_WIH1);
  u16*   WHH1B  = (u16*)(base + OFF_WHH1);
  u16*   SYNB   = (u16*)(base + OFF_SYNB);
  u16*   SEMB   = (u16*)(base + OFF_SEMB);
  float* BASE0  = (float*)(base + OFF_BASE0);
  float* BASEO  = (float*)(base + OFF_BASEO);
  u16*   H0IBF  = (u16*)(base + OFF_H0IBF);
  u16*   H1IBF  = (u16*)(base + OFF_H1IBF);
  int*   FLAGS  = (int*)(base + OFF_FLAGS);
  float* hidf   = (float*)(base + OFF_HIDF);
  float* last   = (float*)(base + OFF_LAST);
  float* logits = (float*)(base + OFF_LOGIT);

  // weight conversions to bf16
  conv_bf16_k<<<16000, 256, 0, stream>>>(Wout, WCAT, 32000, 128, 2560, 0, 1536, 0);
  conv_bf16_k<<<8000, 256, 0, stream>>>(Wout, WCAT, 32000, 64, 2560, 2048, 1536, 1024);
  conv_bf16_k<<<16000, 256, 0, stream>>>(Wout, WSEM, 32000, 128, 2560, 1024, 1024, 0);
  conv_bf16_k<<<768, 256, 0, stream>>>(Wih0, WIH0E, 3072, 64, 1536, 0, 512, 0);
  conv_bf16_k<<<1536, 256, 0, stream>>>(Wih0, WIH0S, 3072, 128, 1536, 512, 1024, 0);
  conv_bf16_k<<<1536, 256, 0, stream>>>(Whh0, WHH0B, 3072, 128, 1024, 0, 1024, 0);
  conv_bf16_k<<<1536, 256, 0, stream>>>(Wih1, WIH1B, 3072, 128, 1024, 0, 1024, 0);
  conv_bf16_k<<<1536, 256, 0, stream>>>(Whh1, WHH1B, 3072, 128, 1024, 0, 1024, 0);

  // embeddings + packed small operands + init
  gather_emb_k<<<512, 256, 0, stream>>>(seq, table, XOUT);
  pack_pad_bf16_k<<<64, 256, 0, stream>>>(syn, SYNB);
  pack_pad_bf16_k<<<64, 256, 0, stream>>>(sem, SEMB);
  init_h_k<<<64, 256, 0, stream>>>(hidden, H0IBF, H1IBF, FLAGS);

  // time-invariant bases via MFMA GEMM (M padded to 128; rows 16..127 junk)
  gemm_bt_k<2><<<dim3(1, 24), 256, 0, stream>>>(
      SYNB, 1024, WIH0S, 1024, BASE0, 3072, bih0, 3072, 1024);
  gemm_bt_k<2><<<dim3(1, 250), 256, 0, stream>>>(
      SEMB, 1024, WSEM, 1024, BASEO, 32000, bout, 32000, 1024);

  // gi0 for all t: embs @ Wih0e.T + base0
  gemm_bt_k<1><<<dim3(16, 24), 256, 0, stream>>>(
      XOUT + 1024, 1536, WIH0E, 512, GI0, 3072, BASE0, 3072, 512);

  // persistent recurrence: 192 blocks, LDS-resident weights, dataflow sync
  hipFuncSetAttribute((const void*)gru_persist3_k,
                      hipFuncAttributeMaxDynamicSharedMemorySize, 143360);
  gru_persist3_k<<<192, 256, 143360, stream>>>(
      hidden, H0IBF, H1IBF, GI0, WHH0B, WIH1B, WHH1B, bhh0, bih1, bhh1,
      H0ALL, H1ALL, XOUT, PART, hidf, last, FLAGS);

  // logits = [h1 | emb] @ WCAT.T + baseo
  gemm_bt_k<1><<<dim3(16, 250), 256, 0, stream>>>(
      XOUT, 1536, WCAT, 1536, logits, 32000, BASEO, 32000, 1536);

  // scores = log_softmax(logits) — the only writer of the scores region
  log_softmax_k<<<2048, 256, 0, stream>>>(logits, scores);
}